// Round 8
// baseline (31.166 us; speedup 1.0000x reference)
//
#include <hip/hip_runtime.h>
#include <hip/hip_bf16.h>

// y = relu(x @ W1 + b1) @ W2 + b2
// x:[B,64] f32, W1:[64,128], b1:[128], W2:[128,32], b2:[32], y:[B,32] f32
//
// Swapped-operand MFMA structure (lane holds batch row q, 4 consecutive
// h/y cols per acc reg). Weights: block-staged to LDS bf16^T once, read ONCE
// per wave into registers (R6-proven). Biases: per-tile LDS f32 reads.
// h staging: per-wave LDS, uniformly uint2-typed (no aliasing UB).
// x pipeline: grid fixed at 512x256 -> exactly 8 tiles/wave, fully unrolled
// with 3 named register sets (depth-3, ~1350cy cover vs ~900cy HBM latency).
#define B_ROWS   262144
#define N_TILES  (B_ROWS / 16)
#define S_WAVES  2048          // 512 blocks x 4 waves
#define TPW      8             // tiles per wave = N_TILES / S_WAVES

typedef short short8 __attribute__((ext_vector_type(8)));
typedef float f32x4 __attribute__((ext_vector_type(4)));
struct U2x2 { uint2 a, b; };

__device__ inline short f2bf(float f) {
    __hip_bfloat16 h = __float2bfloat16(f);
    return __builtin_bit_cast(short, h);
}
__device__ inline unsigned pk2(float a, float b) {
    unsigned lo = (unsigned short)f2bf(a);
    unsigned hi = (unsigned short)f2bf(b);
    return lo | (hi << 16);
}

__global__ __launch_bounds__(256, 2) void livenet_mlp(
    const float* __restrict__ x, const float* __restrict__ W1,
    const float* __restrict__ b1, const float* __restrict__ W2,
    const float* __restrict__ b2, float* __restrict__ y) {
    __shared__ __align__(16) uint2 hbu[4 * 512];   // per-wave h staging, 16 KB
    __shared__ __align__(16) short w1t[128 * 64];  // W1^T bf16, 16 KB
    __shared__ __align__(16) short w2t[32 * 128];  // W2^T bf16, 8 KB
    __shared__ __align__(16) float bls[160];       // b1 | b2 (f32)

    const int tid  = threadIdx.x;
    const int wid  = tid >> 6;
    const int lane = tid & 63;
    const int g    = lane >> 4;   // k-group 0..3
    const int q    = lane & 15;   // batch row within tile
    uint2* hb = hbu + wid * 512;
    const int key = 2 * (q & 7);  // h-staging colblock XOR key (even)

    // ---- block-cooperative weight staging: global f32 -> LDS bf16^T ----
    // (R6-proven pattern, unswizzled; frag reads below happen ONCE per wave)
#pragma unroll
    for (int p = 0; p < 8; ++p) {              // W1 [64][128]
        const int idx = p * 1024 + tid * 4;
        f32x4 v = *(const f32x4*)(W1 + idx);
        const int k = idx >> 7, c = idx & 127;
#pragma unroll
        for (int e = 0; e < 4; ++e) w1t[(c + e) * 64 + k] = f2bf(v[e]);
    }
#pragma unroll
    for (int p = 0; p < 4; ++p) {              // W2 [128][32]
        const int idx = p * 1024 + tid * 4;
        f32x4 v = *(const f32x4*)(W2 + idx);
        const int k = idx >> 5, o = idx & 31;
#pragma unroll
        for (int e = 0; e < 4; ++e) w2t[(o + e) * 128 + k] = f2bf(v[e]);
    }
    if (tid < 128) bls[tid] = b1[tid];
    else if (tid < 160) bls[tid] = b2[tid - 128];
    __syncthreads();

    // ---- weight fragments: LDS -> registers, ONCE per wave ----
    // w1f[ks][n] elem j = bf16(W1[32ks+8g+j][16n+q]); same form for w2f
    short8 w1f[2][8];
#pragma unroll
    for (int ks = 0; ks < 2; ++ks)
#pragma unroll
        for (int n = 0; n < 8; ++n)
            w1f[ks][n] = *(const short8*)&w1t[(n * 16 + q) * 64 + ks * 32 + g * 8];
    short8 w2f[4][2];
#pragma unroll
    for (int ks = 0; ks < 4; ++ks)
#pragma unroll
        for (int n = 0; n < 2; ++n)
            w2f[ks][n] = *(const short8*)&w2t[(n * 16 + q) * 128 + ks * 32 + g * 8];

    const int gwave = blockIdx.x * 4 + wid;                 // 0..2047
    const float* xw = x + (size_t)gwave * 1024 + (size_t)q * 64 + g * 8;
    float*       yw = y + (size_t)(gwave * 16 + q) * 32 + 4 * g;

    // ---- three named f32x4 register sets; tile(k) = gwave + k*2048 ----
    f32x4 S00, S01, S02, S03, S10, S11, S12, S13, S20, S21, S22, S23;

#define XLOAD(A0, A1, A2, A3, K)                                              \
    {                                                                         \
        const f32x4* p_ = (const f32x4*)(xw + (size_t)(K) * 2097152);         \
        A0 = p_[0]; A1 = p_[1]; A2 = p_[8]; A3 = p_[9];                       \
    }

    XLOAD(S00, S01, S02, S03, 0)
    XLOAD(S10, S11, S12, S13, 1)
    XLOAD(S20, S21, S22, S23, 2)

#define BODY(K, A0, A1, A2, A3)                                               \
    {                                                                         \
        /* convert set -> bf16 B-frags: elem j = x[row q][32ks+8g+j] */       \
        short8 a0, a1;                                                        \
        {                                                                     \
            short8 v;                                                         \
            v[0] = f2bf(A0[0]); v[1] = f2bf(A0[1]);                           \
            v[2] = f2bf(A0[2]); v[3] = f2bf(A0[3]);                           \
            v[4] = f2bf(A1[0]); v[5] = f2bf(A1[1]);                           \
            v[6] = f2bf(A1[2]); v[7] = f2bf(A1[3]);                           \
            a0 = v;                                                           \
            v[0] = f2bf(A2[0]); v[1] = f2bf(A2[1]);                           \
            v[2] = f2bf(A2[2]); v[3] = f2bf(A2[3]);                           \
            v[4] = f2bf(A3[0]); v[5] = f2bf(A3[1]);                           \
            v[6] = f2bf(A3[2]); v[7] = f2bf(A3[3]);                           \
            a1 = v;                                                           \
        }                                                                     \
        /* refill this set with tile K+3 (compile-time elided at tail) */     \
        if ((K) + 3 < TPW) XLOAD(A0, A1, A2, A3, (K) + 3)                     \
        /* GEMM1 (swapped): lane reg r = h[row q][16n+4g+r] */                \
        f32x4 acc1[8];                                                        \
        _Pragma("unroll")                                                     \
        for (int n = 0; n < 8; ++n) {                                         \
            acc1[n] = *(const f32x4*)&bls[n * 16 + 4 * g];                    \
            acc1[n] = __builtin_amdgcn_mfma_f32_16x16x32_bf16(                \
                w1f[0][n], a0, acc1[n], 0, 0, 0);                             \
            acc1[n] = __builtin_amdgcn_mfma_f32_16x16x32_bf16(                \
                w1f[1][n], a1, acc1[n], 0, 0, 0);                             \
        }                                                                     \
        /* ReLU + pack 4 consecutive cols -> one uint2 LDS write per n */     \
        _Pragma("unroll")                                                     \
        for (int n = 0; n < 8; ++n) {                                         \
            uint2 w;                                                          \
            w.x = pk2(fmaxf(acc1[n][0], 0.0f), fmaxf(acc1[n][1], 0.0f));      \
            w.y = pk2(fmaxf(acc1[n][2], 0.0f), fmaxf(acc1[n][3], 0.0f));      \
            hb[q * 32 + ((4 * n + g) ^ key)] = w;                             \
        }                                                                     \
        /* read h B-frags: elem j = h[row q][32ks+8g+j] (uint2-typed) */      \
        short8 ha[4];                                                         \
        _Pragma("unroll")                                                     \
        for (int ks = 0; ks < 4; ++ks) {                                      \
            const int jj = q * 32 + ((8 * ks + 2 * g) ^ key);                 \
            U2x2 t_{hb[jj], hb[jj + 1]};                                      \
            ha[ks] = __builtin_bit_cast(short8, t_);                          \
        }                                                                     \
        /* GEMM2 (swapped): lane reg r = y[row q][16n+4g+r] */                \
        f32x4 acc2[2];                                                        \
        _Pragma("unroll")                                                     \
        for (int n = 0; n < 2; ++n) {                                         \
            acc2[n] = *(const f32x4*)&bls[128 + n * 16 + 4 * g];              \
            _Pragma("unroll")                                                 \
            for (int ks = 0; ks < 4; ++ks)                                    \
                acc2[n] = __builtin_amdgcn_mfma_f32_16x16x32_bf16(            \
                    w2f[ks][n], ha[ks], acc2[n], 0, 0, 0);                    \
        }                                                                     \
        _Pragma("unroll")                                                     \
        for (int n = 0; n < 2; ++n)                                           \
            __builtin_nontemporal_store(                                      \
                acc2[n], (f32x4*)(yw + (size_t)(K) * 1048576 + n * 16));      \
    }

    BODY(0, S00, S01, S02, S03)
    BODY(1, S10, S11, S12, S13)
    BODY(2, S20, S21, S22, S23)
    BODY(3, S00, S01, S02, S03)
    BODY(4, S10, S11, S12, S13)
    BODY(5, S20, S21, S22, S23)
    BODY(6, S00, S01, S02, S03)
    BODY(7, S10, S11, S12, S13)

#undef BODY
#undef XLOAD
}

extern "C" void kernel_launch(void* const* d_in, const int* in_sizes, int n_in,
                              void* d_out, int out_size, void* d_ws, size_t ws_size,
                              hipStream_t stream) {
    const float* x  = (const float*)d_in[0];
    const float* W1 = (const float*)d_in[1];
    const float* b1 = (const float*)d_in[2];
    const float* W2 = (const float*)d_in[3];
    const float* b2 = (const float*)d_in[4];
    float* y = (float*)d_out;

    // Fixed geometry: 512 blocks x 256 threads = 2048 waves, 8 tiles each.
    livenet_mlp<<<512, 256, 0, stream>>>(x, W1, b1, W2, b2, y);
}